// Round 6
// baseline (170.585 us; speedup 1.0000x reference)
//
#include <hip/hip_runtime.h>
#include <hip/hip_bf16.h>
#include <stdint.h>

// ECG beat tokenizer: X[196608, 64] = ecg_rows[196608, 128] @ W[64,128]^T + b
// plus beat_intervals[128*128] = 128.0f appended at out + 196608*64.
//
// R6: global_load_lds pipeline. R2-R5 diagnosis: compiler serialized the
// A loads (VGPR=60 vs ~115 needed; duration invariant to HBM traffic; all
// pipes idle) -> latency-bound at ~55-60us. Fix: width-16 global_load_lds
// (no VGPR results, hardware queue), per-wave PRIVATE 8KB sub-tiles (zero
// main-loop barriers), 2-deep double-buffer with counted vmcnt(12), and
// XOR-swizzled LDS layout via pre-swizzled global source (linear dest).
// 512 blocks x 256 thr, 80KB LDS, 2 blocks/CU, 6 tiles of 64 rows each.

#define BEAT_LEN   128
#define TOKEN_DIM  64
#define N_BATCH    128
#define N_BEATS    128
#define M_ROWS     196608
#define TM         64                  // rows per tile
#define NT         6                   // tiles per block
#define WPB        4
#define NBLOCKS    (M_ROWS / (NT * TM))   // 512

typedef __attribute__((ext_vector_type(4))) float    f32x4;
typedef __attribute__((ext_vector_type(8))) short    bf16x8;
typedef __attribute__((ext_vector_type(4))) uint32_t u32x4;

// round-half-up pack (W only; one-time, best accuracy)
__device__ __forceinline__ uint32_t pkbf16(float a, float b) {
    uint32_t ua = __float_as_uint(a);
    uint32_t ub = __float_as_uint(b);
    return ((ua + 0x8000u) >> 16) | ((ub + 0x8000u) & 0xffff0000u);
}
__device__ __forceinline__ bf16x8 pack8(f32x4 lo, f32x4 hi) {
    u32x4 u;
    u.x = pkbf16(lo[0], lo[1]);
    u.y = pkbf16(lo[2], lo[3]);
    u.z = pkbf16(hi[0], hi[1]);
    u.w = pkbf16(hi[2], hi[3]);
    return __builtin_bit_cast(bf16x8, u);
}
// truncating pack via one v_perm_b32: [hi16(b) : hi16(a)]
__device__ __forceinline__ uint32_t pktr(float a, float b) {
    return __builtin_amdgcn_perm(__float_as_uint(a), __float_as_uint(b),
                                 0x03020706u);
}
__device__ __forceinline__ bf16x8 pack8t(f32x4 lo, f32x4 hi) {
    u32x4 u;
    u.x = pktr(lo[0], lo[1]);
    u.y = pktr(lo[2], lo[3]);
    u.z = pktr(hi[0], hi[1]);
    u.w = pktr(hi[2], hi[3]);
    return __builtin_bit_cast(bf16x8, u);
}

// async global -> LDS, 16B per lane (lane l writes ldsbase + l*16)
__device__ __forceinline__ void gload16(const float* g, void* l) {
    __builtin_amdgcn_global_load_lds(
        (const __attribute__((address_space(1))) void*)g,
        (__attribute__((address_space(3))) void*)l,
        16, 0, 0);
}
template<int N> __device__ __forceinline__ void wait_vm() {
    asm volatile("s_waitcnt vmcnt(%0)" :: "n"(N) : "memory");
}

__global__ __launch_bounds__(256) void ECGTokenizer_53420803228140_kernel(
    const float* __restrict__ ecg, const float* __restrict__ W,
    const float* __restrict__ b, float* __restrict__ out)
{
    // A tiles: [2 buffers][64 rows][32 chunks of 16B], linear dest for
    // global_load_lds; slot (row,k) holds logical chunk k ^ (row&7)
    // (achieved by XOR-ing the SOURCE address per lane).
    __shared__ __align__(16) uint8_t abuf[2][TM * 512];   // 2 x 32 KiB
    // W fragments, fragment-major: slice (c*4+s) = 64 lanes x 16B
    __shared__ __align__(16) uint8_t wlds[16384];         // 16 KiB

    const int tid  = threadIdx.x;
    const int lane = tid & 63;
    const int wid  = tid >> 6;
    const int l16  = lane & 15;
    const int lg   = lane >> 4;
    const size_t blk_row0 = (size_t)blockIdx.x * (NT * TM);

    // issue this wave's 8 gload_lds (8KB private sub-tile) for tile t
    auto issue = [&](int t, int bufsel) {
        #pragma unroll
        for (int j = 0; j < 8; ++j) {
            const int rib = (wid << 4) + (j << 1) + (lane >> 5); // row in tile
            const int ks  = (lane & 31) ^ (rib & 7);             // src chunk
            const float* src = ecg
                + (blk_row0 + (size_t)t * TM + rib) * BEAT_LEN + ks * 4;
            gload16(src, &abuf[bufsel][((wid << 4) + (j << 1)) * 512]);
        }
    };

    // ---- prologue: start tiles 0 and 1 immediately ----
    issue(0, 0);
    issue(1, 1);

    // ---- stage W (32 KB fp32 -> 16 KB bf16) under the A latency ----
    for (int ch = tid; ch < 1024; ch += 256) {
        const int slice = ch >> 6, ln = ch & 63;
        const int c = slice >> 2, s = slice & 3;
        const int sl16 = ln & 15, slg = ln >> 4;
        const float* wp = W + (16*c + sl16)*BEAT_LEN + 32*s + 8*slg;
        f32x4 w0 = *(const f32x4*)(wp);
        f32x4 w1 = *(const f32x4*)(wp + 4);
        *(bf16x8*)&wlds[ch * 16] = pack8(w0, w1);
    }
    // bias: lane's 4 acc entries are d = 16c + 4*lg + {0..3}
    f32x4 bvv[4];
    #pragma unroll
    for (int c = 0; c < 4; ++c) bvv[c] = *(const f32x4*)(b + 16*c + 4*lg);

    __syncthreads();   // W ready; drains prologue gloads too (one-time)

    // ---- main loop: zero barriers (per-wave private sub-tiles) ----
    #pragma unroll
    for (int t = 0; t < NT; ++t) {
        const int cur = t & 1;
        // steady state: newer-than-tile-t ops = 4 stores + 8 gloads = 12
        if (t + 1 < NT) wait_vm<12>(); else wait_vm<4>();

        const int rib = (wid << 4) + l16;              // this lane's row
        const uint8_t* arow = &abuf[cur][rib * 512];
        bf16x8 af[4];
        #pragma unroll
        for (int s = 0; s < 4; ++s) {
            const int c0 = 8*s + 2*lg;
            const int k0 = c0 ^ (l16 & 7);
            const int k1 = (c0 + 1) ^ (l16 & 7);
            f32x4 a0 = *(const f32x4*)(arow + k0 * 16);
            f32x4 a1 = *(const f32x4*)(arow + k1 * 16);
            af[s] = pack8t(a0, a1);
        }

        f32x4 acc[4];
        #pragma unroll
        for (int c = 0; c < 4; ++c) acc[c] = bvv[c];
        #pragma unroll
        for (int s = 0; s < 4; ++s) {
            #pragma unroll
            for (int c = 0; c < 4; ++c) {
                bf16x8 wf = *(const bf16x8*)&wlds[((c*4 + s)*64 + lane) * 16];
                acc[c] = __builtin_amdgcn_mfma_f32_16x16x32_bf16(
                             wf, af[s], acc[c], 0, 0, 0);
            }
        }

        // D: token dim = 16c + 4*lg + reg, ecg row = rib (verified R3-R5)
        float* orow = out + (blk_row0 + (size_t)t * TM + rib) * TOKEN_DIM
                    + 4 * lg;
        #pragma unroll
        for (int c = 0; c < 4; ++c) {
            __builtin_nontemporal_store(acc[c], (f32x4*)(orow + 16*c));
        }

        // refill the buffer we just consumed (own region only -> no barrier)
        if (t + 2 < NT) issue(t + 2, cur);
    }

    // beat_intervals [128,128] = 128.0f, appended after X
    const int gtid = blockIdx.x * blockDim.x + threadIdx.x;
    if (gtid < N_BATCH * N_BEATS) {
        out[(size_t)M_ROWS * TOKEN_DIM + gtid] = 128.0f;
    }
}

extern "C" void kernel_launch(void* const* d_in, const int* in_sizes, int n_in,
                              void* d_out, int out_size, void* d_ws, size_t ws_size,
                              hipStream_t stream) {
    const float* ecg = (const float*)d_in[0];
    const float* W   = (const float*)d_in[1];
    const float* b   = (const float*)d_in[2];
    float* out       = (float*)d_out;
    hipLaunchKernelGGL(ECGTokenizer_53420803228140_kernel,
                       dim3(NBLOCKS), dim3(256), 0, stream,
                       ecg, W, b, out);
}

// Round 7
// 165.407 us; speedup vs baseline: 1.0313x; 1.0313x over previous
//
#include <hip/hip_runtime.h>
#include <hip/hip_bf16.h>
#include <stdint.h>

// ECG beat tokenizer: X[196608, 64] = ecg_rows[196608, 128] @ W[64,128]^T + b
// plus beat_intervals[128*128] = 128.0f appended at out + 196608*64.
//
// R7: copy-like kernel. Two changes vs R3-R6 (which were all ~54-60us):
//  1. STREAMING STORES: LDS transpose epilogue (per-wave private 4KB,
//     XOR-swizzled) so each store instr writes a contiguous 1KB of FULL
//     cache lines. Evidence: FETCH_SIZE==49.3MB ~= output size in R2&R5
//     (suspected write-allocate RFO on partial-line stores; the 6.8TB/s
//     fills write full lines and show FETCH~0).
//  2. HIGH TLP: one 16-row group per wave, 3072 blocks, 32KB LDS,
//     launch_bounds(256,5) -> 5 blocks/CU = 20 waves/CU, 8 independent
//     upfront loads/wave, zero loop-carried dependence.

#define BEAT_LEN   128
#define TOKEN_DIM  64
#define N_BATCH    128
#define N_BEATS    128
#define M_ROWS     196608
#define RGROUPS    (M_ROWS / 16)     // 12288
#define WPB        4
#define NBLOCKS    (RGROUPS / WPB)   // 3072: exactly one row-group per wave

typedef __attribute__((ext_vector_type(4))) float    f32x4;
typedef __attribute__((ext_vector_type(8))) short    bf16x8;
typedef __attribute__((ext_vector_type(4))) uint32_t u32x4;

// round-half-up pack (W only; one-time, best accuracy)
__device__ __forceinline__ uint32_t pkbf16(float a, float b) {
    uint32_t ua = __float_as_uint(a);
    uint32_t ub = __float_as_uint(b);
    return ((ua + 0x8000u) >> 16) | ((ub + 0x8000u) & 0xffff0000u);
}
__device__ __forceinline__ bf16x8 pack8(f32x4 lo, f32x4 hi) {
    u32x4 u;
    u.x = pkbf16(lo[0], lo[1]);
    u.y = pkbf16(lo[2], lo[3]);
    u.z = pkbf16(hi[0], hi[1]);
    u.w = pkbf16(hi[2], hi[3]);
    return __builtin_bit_cast(bf16x8, u);
}
// truncating pack via one v_perm_b32: [hi16(b) : hi16(a)]
__device__ __forceinline__ uint32_t pktr(float a, float b) {
    return __builtin_amdgcn_perm(__float_as_uint(a), __float_as_uint(b),
                                 0x03020706u);
}
__device__ __forceinline__ bf16x8 pack8t(f32x4 lo, f32x4 hi) {
    u32x4 u;
    u.x = pktr(lo[0], lo[1]);
    u.y = pktr(lo[2], lo[3]);
    u.z = pktr(hi[0], hi[1]);
    u.w = pktr(hi[2], hi[3]);
    return __builtin_bit_cast(bf16x8, u);
}

__global__ __launch_bounds__(256, 5) void ECGTokenizer_53420803228140_kernel(
    const float* __restrict__ ecg, const float* __restrict__ W,
    const float* __restrict__ b, float* __restrict__ out)
{
    // W fragments, fragment-major: slice (c*4+s) = 64 lanes x 16B  (16 KiB)
    __shared__ __align__(16) uint8_t wlds[16384];
    // per-wave transpose region: [16 rows][256 B], XOR-swizzled  (16 KiB)
    __shared__ __align__(16) uint8_t tlds[WPB][4096];

    const int tid  = threadIdx.x;
    const int lane = tid & 63;
    const int wid  = tid >> 6;
    const int l16  = lane & 15;
    const int lg   = lane >> 4;
    const int rg   = blockIdx.x * WPB + wid;   // one 16-row group per wave

    // ---- all 8 A loads upfront (independent; HBM latency shared) ----
    const float* arow = ecg + (size_t)rg * (16 * BEAT_LEN)
                      + (size_t)l16 * BEAT_LEN + 8 * lg;
    f32x4 a0[4], a1[4];
    #pragma unroll
    for (int s = 0; s < 4; ++s) {
        a0[s] = *(const f32x4*)(arow + 32*s);
        a1[s] = *(const f32x4*)(arow + 32*s + 4);
    }

    // ---- stage W (32 KB fp32 -> 16 KB bf16) under the A latency ----
    for (int ch = tid; ch < 1024; ch += 256) {
        const int slice = ch >> 6, ln = ch & 63;
        const int c = slice >> 2, s = slice & 3;
        const int sl16 = ln & 15, slg = ln >> 4;
        const float* wp = W + (16*c + sl16)*BEAT_LEN + 32*s + 8*slg;
        f32x4 w0 = *(const f32x4*)(wp);
        f32x4 w1 = *(const f32x4*)(wp + 4);
        *(bf16x8*)&wlds[ch * 16] = pack8(w0, w1);
    }
    // bias for the streaming epilogue: lane holds cols 4*l16 .. +3
    const f32x4 bias4 = *(const f32x4*)(b + 4 * l16);
    __syncthreads();

    // ---- MFMA: acc[c] holds (d = 16c + 4*lg + r, m-row = l16), bias later
    f32x4 acc[4];
    #pragma unroll
    for (int c = 0; c < 4; ++c) acc[c] = (f32x4){0.f, 0.f, 0.f, 0.f};
    #pragma unroll
    for (int s = 0; s < 4; ++s) {
        bf16x8 af = pack8t(a0[s], a1[s]);
        #pragma unroll
        for (int c = 0; c < 4; ++c) {
            bf16x8 wf = *(const bf16x8*)&wlds[((c*4 + s)*64 + lane) * 16];
            acc[c] = __builtin_amdgcn_mfma_f32_16x16x32_bf16(
                         wf, af, acc[c], 0, 0, 0);
        }
    }

    // ---- transpose epilogue (wave-private region, no barrier) ----
    // slot s of row m lives at byte m*256 + 16*(s ^ (m&7))  (bijective)
    uint8_t* tw = tlds[wid];
    #pragma unroll
    for (int c = 0; c < 4; ++c) {
        const int slot = 4*c + lg;                 // d-chunk (16c+4lg)/4
        *(f32x4*)&tw[l16*256 + 16*(slot ^ (l16 & 7))] = acc[c];
    }
    // read back in streaming order: instr j -> lane covers out floats
    // [rg*1024 + j*256 + lane*4, +4)  => wave writes contiguous 1 KB
    float* obase = out + (size_t)rg * (16 * TOKEN_DIM);
    #pragma unroll
    for (int j = 0; j < 4; ++j) {
        const int m = 4*j + lg;                    // row within group
        f32x4 t = *(const f32x4*)&tw[m*256 + 16*(l16 ^ (m & 7))];
        t += bias4;
        __builtin_nontemporal_store(t, (f32x4*)(obase + j*256 + lane*4));
    }

    // beat_intervals [128,128] = 128.0f, appended after X
    const int gtid = blockIdx.x * blockDim.x + threadIdx.x;
    if (gtid < N_BATCH * N_BEATS) {
        out[(size_t)M_ROWS * TOKEN_DIM + gtid] = 128.0f;
    }
}

extern "C" void kernel_launch(void* const* d_in, const int* in_sizes, int n_in,
                              void* d_out, int out_size, void* d_ws, size_t ws_size,
                              hipStream_t stream) {
    const float* ecg = (const float*)d_in[0];
    const float* W   = (const float*)d_in[1];
    const float* b   = (const float*)d_in[2];
    float* out       = (float*)d_out;
    hipLaunchKernelGGL(ECGTokenizer_53420803228140_kernel,
                       dim3(NBLOCKS), dim3(256), 0, stream,
                       ecg, W, b, out);
}